// Round 1
// baseline (7240.609 us; speedup 1.0000x reference)
//
#include <hip/hip_runtime.h>

// Fused per-batch graph encoder. One 512-thread block (8 waves) per batch
// element; all activations in LDS; weights register-cached per wave
// (lane c holds W[:,c]); LayerNorm via 64-lane shfl_xor reductions.

#define BLK 512
#define NHX 19
#define NVX 54
#define NED 72
#define TF  32
#define HD  64

__device__ __forceinline__ float wsum64(float v){
#pragma unroll
  for (int m = 32; m >= 1; m >>= 1) v += __shfl_xor(v, m, 64);
  return v;
}

template<int KK>
__device__ __forceinline__ float dot_seg(const float* xrow, const float* w){
  float acc = 0.f;
#pragma unroll
  for (int q = 0; q < KK/4; ++q){
    float4 x = ((const float4*)xrow)[q];
    acc = fmaf(x.x, w[4*q+0], acc);
    acc = fmaf(x.y, w[4*q+1], acc);
    acc = fmaf(x.z, w[4*q+2], acc);
    acc = fmaf(x.w, w[4*q+3], acc);
  }
  return acc;
}

template<int K>
__device__ __forceinline__ void load_w(float* w, const float* __restrict__ Wg, int lane){
#pragma unroll
  for (int k = 0; k < K; ++k) w[k] = Wg[k*HD + lane];
}

__device__ __forceinline__ void ln_relu_store(float acc, int lane, float gv, float bev, float* dst){
  float mu  = wsum64(acc) * (1.f/(float)HD);
  float d   = acc - mu;
  float var = wsum64(d*d) * (1.f/(float)HD);
  float y   = fmaf(d * rsqrtf(var + 1e-5f), gv, bev);
  dst[lane] = fmaxf(y, 0.f);
}

__global__ __launch_bounds__(BLK, 2)
void graph_enc_kernel(
    const float* __restrict__ tile,
    const int* __restrict__ h2v, const int* __restrict__ v2h,
    const int* __restrict__ e2v, const int* __restrict__ v2e,
    const float* __restrict__ hinW, const float* __restrict__ hinb,
    const float* __restrict__ hing, const float* __restrict__ hinbe,
    const float* __restrict__ vinW, const float* __restrict__ vinb,
    const float* __restrict__ ving, const float* __restrict__ vinbe,
    const float* __restrict__ einW, const float* __restrict__ einb,
    const float* __restrict__ eing, const float* __restrict__ einbe,
    const float* __restrict__ huW, const float* __restrict__ hub,
    const float* __restrict__ hug, const float* __restrict__ hube,
    const float* __restrict__ vuW, const float* __restrict__ vub,
    const float* __restrict__ vug, const float* __restrict__ vube,
    const float* __restrict__ euW, const float* __restrict__ eub,
    const float* __restrict__ eug, const float* __restrict__ eube,
    const float* __restrict__ roW, const float* __restrict__ rob,
    const float* __restrict__ rog, const float* __restrict__ robe,
    float* __restrict__ out)
{
  // LDS layout (floats): acts 9280, gathers 12736, raws 4640, pool 192 = 26848 f = 107,392 B
  __shared__ float sm[26848];
  float* s_hex  = sm;                    // 19*64
  float* s_vtx  = s_hex  + NHX*HD;       // 54*64
  float* s_edge = s_vtx  + NVX*HD;       // 72*64
  float* g_h    = s_edge + NED*HD;       // 19*64  (h_from_v)
  float* g_vh   = g_h    + NHX*HD;       // 54*64  (v_from_h)
  float* g_ve   = g_vh   + NVX*HD;       // 54*64  (v_from_e)
  float* g_e    = g_ve   + NVX*HD;       // 72*64  (e_from_v)
  float* s_tile = g_e    + NED*HD;       // 19*32
  float* s_vraw = s_tile + NHX*TF;       // 54*32
  float* s_eraw = s_vraw + NVX*TF;       // 72*32
  float* s_pool = s_eraw + NED*TF;       // 192

  const int b    = blockIdx.x;
  const int t    = threadIdx.x;
  const int lane = t & 63;
  const int wv   = t >> 6;

  // ---- stage tile features into LDS ----
  const float* tsrc = tile + (size_t)b * (NHX*TF);
  for (int i = t; i < NHX*TF; i += BLK) s_tile[i] = tsrc[i];
  __syncthreads();

  // ---- vertex_raw = masked-avg gather of tile over v2h ----
  for (int e = t; e < NVX*TF; e += BLK){
    int v = e >> 5, k = e & 31;
    float s = 0.f; int c = 0;
#pragma unroll
    for (int j = 0; j < 3; ++j){
      int ix = v2h[v*3+j];
      if (ix >= 0){ s += s_tile[ix*TF + k]; c++; }
    }
    s_vraw[e] = s / (float)(c > 0 ? c : 1);
  }
  __syncthreads();

  // ---- edge_raw = masked-avg gather of vertex_raw over e2v ----
  for (int e = t; e < NED*TF; e += BLK){
    int ed = e >> 5, k = e & 31;
    float s = 0.f; int c = 0;
#pragma unroll
    for (int j = 0; j < 2; ++j){
      int ix = e2v[ed*2+j];
      if (ix >= 0){ s += s_vraw[ix*TF + k]; c++; }
    }
    s_eraw[e] = s / (float)(c > 0 ? c : 1);
  }
  __syncthreads();

  float wreg[192];

  // ---- stage-0 input GEMMs (K=32) : hex=1 wave, vtx=3 waves, edge=4 waves ----
  if (wv == 0){
    load_w<32>(wreg, hinW, lane);
    float gv = hing[lane], bev = hinbe[lane], bv = hinb[lane];
    for (int n = 0; n < NHX; ++n){
      float acc = bv + dot_seg<32>(s_tile + n*TF, wreg);
      ln_relu_store(acc, lane, gv, bev, s_hex + n*HD);
    }
  } else if (wv <= 3){
    load_w<32>(wreg, vinW, lane);
    float gv = ving[lane], bev = vinbe[lane], bv = vinb[lane];
    for (int n = wv-1; n < NVX; n += 3){
      float acc = bv + dot_seg<32>(s_vraw + n*TF, wreg);
      ln_relu_store(acc, lane, gv, bev, s_vtx + n*HD);
    }
  } else {
    load_w<32>(wreg, einW, lane);
    float gv = eing[lane], bev = einbe[lane], bv = einb[lane];
    for (int n = wv-4; n < NED; n += 4){
      float acc = bv + dot_seg<32>(s_eraw + n*TF, wreg);
      ln_relu_store(acc, lane, gv, bev, s_edge + n*HD);
    }
  }
  __syncthreads();

  // ---- 2 message-passing rounds ----
  for (int r = 0; r < 2; ++r){
    // gathers (read old acts, write gather buffers)
    for (int e = t; e < NHX*HD; e += BLK){
      int h = e >> 6, c = e & 63;
      float s = 0.f; int cnt = 0;
#pragma unroll
      for (int j = 0; j < 6; ++j){
        int ix = h2v[h*6+j];
        if (ix >= 0){ s += s_vtx[ix*HD + c]; cnt++; }
      }
      g_h[e] = s / (float)(cnt > 0 ? cnt : 1);
    }
    for (int e = t; e < NVX*HD; e += BLK){
      int v = e >> 6, c = e & 63;
      float s = 0.f; int cnt = 0;
#pragma unroll
      for (int j = 0; j < 3; ++j){
        int ix = v2h[v*3+j];
        if (ix >= 0){ s += s_hex[ix*HD + c]; cnt++; }
      }
      g_vh[e] = s / (float)(cnt > 0 ? cnt : 1);
      s = 0.f; cnt = 0;
#pragma unroll
      for (int j = 0; j < 3; ++j){
        int ix = v2e[v*3+j];
        if (ix >= 0){ s += s_edge[ix*HD + c]; cnt++; }
      }
      g_ve[e] = s / (float)(cnt > 0 ? cnt : 1);
    }
    for (int e = t; e < NED*HD; e += BLK){
      int ed = e >> 6, c = e & 63;
      float s = 0.f; int cnt = 0;
#pragma unroll
      for (int j = 0; j < 2; ++j){
        int ix = e2v[ed*2+j];
        if (ix >= 0){ s += s_vtx[ix*HD + c]; cnt++; }
      }
      g_e[e] = s / (float)(cnt > 0 ? cnt : 1);
    }
    __syncthreads();

    // updates (in-place per row; rows disjoint across waves)
    if (wv == 0){
      load_w<128>(wreg, huW + r*128*HD, lane);
      float gv = hug[r*HD+lane], bev = hube[r*HD+lane], bv = hub[r*HD+lane];
      for (int n = 0; n < NHX; ++n){
        float acc = bv + dot_seg<64>(s_hex + n*HD, wreg)
                       + dot_seg<64>(g_h   + n*HD, wreg + 64);
        ln_relu_store(acc, lane, gv, bev, s_hex + n*HD);
      }
    } else if (wv <= 4){
      load_w<192>(wreg, vuW + r*192*HD, lane);
      float gv = vug[r*HD+lane], bev = vube[r*HD+lane], bv = vub[r*HD+lane];
      for (int n = wv-1; n < NVX; n += 4){
        float acc = bv + dot_seg<64>(s_vtx + n*HD, wreg)
                       + dot_seg<64>(g_vh  + n*HD, wreg + 64)
                       + dot_seg<64>(g_ve  + n*HD, wreg + 128);
        ln_relu_store(acc, lane, gv, bev, s_vtx + n*HD);
      }
    } else {
      load_w<128>(wreg, euW + r*128*HD, lane);
      float gv = eug[r*HD+lane], bev = eube[r*HD+lane], bv = eub[r*HD+lane];
      for (int n = wv-5; n < NED; n += 3){
        float acc = bv + dot_seg<64>(s_edge + n*HD, wreg)
                       + dot_seg<64>(g_e    + n*HD, wreg + 64);
        ln_relu_store(acc, lane, gv, bev, s_edge + n*HD);
      }
    }
    __syncthreads();
  }

  // ---- pooling: mean over nodes per channel ----
  if (t < 192){
    int c = t & 63, ty = t >> 6;
    float s = 0.f;
    if (ty == 0){
      for (int n = 0; n < NHX; ++n) s += s_hex[n*HD + c];
      s *= (1.f/(float)NHX);
    } else if (ty == 1){
      for (int n = 0; n < NVX; ++n) s += s_vtx[n*HD + c];
      s *= (1.f/(float)NVX);
    } else {
      for (int n = 0; n < NED; ++n) s += s_edge[n*HD + c];
      s *= (1.f/(float)NED);
    }
    s_pool[t] = s;
  }
  __syncthreads();

  // ---- readout (single row, wave 0) ----
  if (wv == 0){
    load_w<192>(wreg, roW, lane);
    float acc = rob[lane] + dot_seg<192>(s_pool, wreg);
    float mu  = wsum64(acc) * (1.f/(float)HD);
    float d   = acc - mu;
    float var = wsum64(d*d) * (1.f/(float)HD);
    float y   = fmaf(d * rsqrtf(var + 1e-5f), rog[lane], robe[lane]);
    out[(size_t)b*HD + lane] = fmaxf(y, 0.f);
  }
}

extern "C" void kernel_launch(void* const* d_in, const int* in_sizes, int n_in,
                              void* d_out, int out_size, void* d_ws, size_t ws_size,
                              hipStream_t stream) {
  const float* tile = (const float*)d_in[0];
  const int* h2v  = (const int*)d_in[1];
  const int* v2h  = (const int*)d_in[2];
  const int* e2v  = (const int*)d_in[3];
  const int* v2e  = (const int*)d_in[4];
  const float* hinW = (const float*)d_in[5];
  const float* hinb = (const float*)d_in[6];
  const float* hing = (const float*)d_in[7];
  const float* hinbe= (const float*)d_in[8];
  const float* vinW = (const float*)d_in[9];
  const float* vinb = (const float*)d_in[10];
  const float* ving = (const float*)d_in[11];
  const float* vinbe= (const float*)d_in[12];
  const float* einW = (const float*)d_in[13];
  const float* einb = (const float*)d_in[14];
  const float* eing = (const float*)d_in[15];
  const float* einbe= (const float*)d_in[16];
  const float* huW  = (const float*)d_in[17];
  const float* hub  = (const float*)d_in[18];
  const float* hug  = (const float*)d_in[19];
  const float* hube = (const float*)d_in[20];
  const float* vuW  = (const float*)d_in[21];
  const float* vub  = (const float*)d_in[22];
  const float* vug  = (const float*)d_in[23];
  const float* vube = (const float*)d_in[24];
  const float* euW  = (const float*)d_in[25];
  const float* eub  = (const float*)d_in[26];
  const float* eug  = (const float*)d_in[27];
  const float* eube = (const float*)d_in[28];
  const float* roW  = (const float*)d_in[29];
  const float* rob  = (const float*)d_in[30];
  const float* rog  = (const float*)d_in[31];
  const float* robe = (const float*)d_in[32];
  float* out = (float*)d_out;

  int B = in_sizes[0] / (NHX*TF);   // 16384
  hipLaunchKernelGGL(graph_enc_kernel, dim3(B), dim3(BLK), 0, stream,
      tile, h2v, v2h, e2v, v2e,
      hinW, hinb, hing, hinbe,
      vinW, vinb, ving, vinbe,
      einW, einb, eing, einbe,
      huW, hub, hug, hube,
      vuW, vub, vug, vube,
      euW, eub, eug, eube,
      roW, rob, rog, robe,
      out);
}

// Round 2
// 6866.269 us; speedup vs baseline: 1.0545x; 1.0545x over previous
//
#include <hip/hip_runtime.h>

// Fused per-batch graph encoder, v2.
// One 512-thread block (8 waves) per batch element, 2 blocks/CU (LDS 77.6 KB).
// Work decomposition: (layer, K-segment-of-64, row-range) tasks per wave;
// each wave register-caches exactly 64 W values per lane, computes partial
// dots with 4 independent accumulators, and ds_add_f32's into a shared acc
// buffer. Gathers are computed on the fly into a per-wave LDS slot.

#define BLK 512
#define NHX 19
#define NVX 54
#define NED 72
#define TF  32
#define HD  64
#define NROWS 145   // 19 + 54 + 72
#define VBASE 19
#define EBASE 73

__device__ __forceinline__ float wsum64(float v){
#pragma unroll
  for (int m = 32; m >= 1; m >>= 1) v += __shfl_xor(v, m, 64);
  return v;
}

__device__ __forceinline__ float ln_relu(float y, float g, float be){
  float mu  = wsum64(y) * (1.f/64.f);
  float d   = y - mu;
  float var = wsum64(d*d) * (1.f/64.f);
  return fmaxf(fmaf(d * rsqrtf(var + 1e-5f), g, be), 0.f);
}

// 64-long dot, x broadcast from LDS as float4, w in registers.
// 4 independent accumulator chains -> issue-bound, not latency-bound.
__device__ __forceinline__ float dot64(const float* x, const float* w){
  float a0=0.f, a1=0.f, a2=0.f, a3=0.f;
  const float4* x4 = (const float4*)x;
#pragma unroll
  for (int q = 0; q < 16; ++q){
    float4 v = x4[q];
    a0 = fmaf(v.x, w[4*q+0], a0);
    a1 = fmaf(v.y, w[4*q+1], a1);
    a2 = fmaf(v.z, w[4*q+2], a2);
    a3 = fmaf(v.w, w[4*q+3], a3);
  }
  return (a0+a1) + (a2+a3);
}

__device__ __forceinline__ float dot32(const float* x, const float* w){
  float a0=0.f, a1=0.f, a2=0.f, a3=0.f;
  const float4* x4 = (const float4*)x;
#pragma unroll
  for (int q = 0; q < 8; ++q){
    float4 v = x4[q];
    a0 = fmaf(v.x, w[4*q+0], a0);
    a1 = fmaf(v.y, w[4*q+1], a1);
    a2 = fmaf(v.z, w[4*q+2], a2);
    a3 = fmaf(v.w, w[4*q+3], a3);
  }
  return (a0+a1) + (a2+a3);
}

// One (W-segment, row-range) task: partial dot of length 64 for rows
// [r0,r1), accumulated atomically into s_acc. idx==nullptr -> self rows.
__device__ __forceinline__ void run_task(
    const float* __restrict__ Wseg,   // W base of this 64-row K segment
    const float* s_acts, float* s_acc, float* slot,
    const int* __restrict__ idx, int deg, int src_base,
    int self_base, int acc_base, int r0, int r1, int lane)
{
  float wreg[64];
#pragma unroll
  for (int k = 0; k < 64; ++k) wreg[k] = Wseg[k*HD + lane];

  for (int row = r0; row < r1; ++row){
    const float* xr;
    if (idx == nullptr){
      xr = s_acts + (self_base + row)*HD;
    } else {
      float s = 0.f; int c = 0;
      for (int j = 0; j < deg; ++j){
        int ix = idx[row*deg + j];
        if (ix >= 0){ s += s_acts[(src_base + ix)*HD + lane]; c++; }
      }
      slot[lane] = s / (float)(c > 0 ? c : 1);
      __builtin_amdgcn_wave_barrier();
      asm volatile("" ::: "memory");
      xr = slot;
    }
    float v = dot64(xr, wreg);
    atomicAdd(&s_acc[(acc_base + row)*HD + lane], v);
  }
}

__global__ __launch_bounds__(BLK, 4)
void graph_enc_kernel(
    const float* __restrict__ tile,
    const int* __restrict__ h2v, const int* __restrict__ v2h,
    const int* __restrict__ e2v, const int* __restrict__ v2e,
    const float* __restrict__ hinW, const float* __restrict__ hinb,
    const float* __restrict__ hing, const float* __restrict__ hinbe,
    const float* __restrict__ vinW, const float* __restrict__ vinb,
    const float* __restrict__ ving, const float* __restrict__ vinbe,
    const float* __restrict__ einW, const float* __restrict__ einb,
    const float* __restrict__ eing, const float* __restrict__ einbe,
    const float* __restrict__ huW, const float* __restrict__ hub,
    const float* __restrict__ hug, const float* __restrict__ hube,
    const float* __restrict__ vuW, const float* __restrict__ vub,
    const float* __restrict__ vug, const float* __restrict__ vube,
    const float* __restrict__ euW, const float* __restrict__ eub,
    const float* __restrict__ eug, const float* __restrict__ eube,
    const float* __restrict__ roW, const float* __restrict__ rob,
    const float* __restrict__ rog, const float* __restrict__ robe,
    float* __restrict__ out)
{
  // 19872 floats = 77.6 KB -> 2 blocks/CU
  __shared__ __align__(16) float sm[19872];
  float* s_acts = sm;            // 145*64 = 9280
  float* s_acc  = sm + 9280;     // 145*64 = 9280 (overlaid: vraw/eraw in stage 0)
  float* s_tile = sm + 18560;    // 19*32 = 608
  float* s_pool = sm + 19168;    // 192
  float* s_slot = sm + 19360;    // 8*64 = 512
  float* s_vraw = s_acc;         // 54*32 = 1728
  float* s_eraw = s_acc + 1728;  // 72*32 = 2304

  const int b    = blockIdx.x;
  const int t    = threadIdx.x;
  const int lane = t & 63;
  const int wv   = t >> 6;
  float* slot = s_slot + wv*HD;

  // ---- stage tile features ----
  const float* tsrc = tile + (size_t)b * (NHX*TF);
  for (int i = t; i < NHX*TF; i += BLK) s_tile[i] = tsrc[i];
  __syncthreads();

  // ---- vertex_raw / edge_raw ----
  for (int e = t; e < NVX*TF; e += BLK){
    int v = e >> 5, k = e & 31;
    float s = 0.f; int c = 0;
#pragma unroll
    for (int j = 0; j < 3; ++j){
      int ix = v2h[v*3+j];
      if (ix >= 0){ s += s_tile[ix*TF + k]; c++; }
    }
    s_vraw[e] = s / (float)(c > 0 ? c : 1);
  }
  __syncthreads();
  for (int e = t; e < NED*TF; e += BLK){
    int ed = e >> 5, k = e & 31;
    float s = 0.f; int c = 0;
#pragma unroll
    for (int j = 0; j < 2; ++j){
      int ix = e2v[ed*2+j];
      if (ix >= 0){ s += s_vraw[ix*TF + k]; c++; }
    }
    s_eraw[e] = s / (float)(c > 0 ? c : 1);
  }
  __syncthreads();

  // ---- stage-0 input layers (K=32), direct LN, balanced ~18 rows/wave ----
  {
    const float *Wp, *bp, *gp, *bep, *xs; int r0, r1, obase;
    if (wv == 0)      { Wp=hinW; bp=hinb; gp=hing; bep=hinbe; xs=s_tile; r0=0;          r1=NHX;   obase=0;     }
    else if (wv <= 3) { Wp=vinW; bp=vinb; gp=ving; bep=vinbe; xs=s_vraw; r0=(wv-1)*18;  r1=r0+18; obase=VBASE; }
    else              { Wp=einW; bp=einb; gp=eing; bep=einbe; xs=s_eraw; r0=(wv-4)*18;  r1=r0+18; obase=EBASE; }
    float wreg[32];
#pragma unroll
    for (int k = 0; k < 32; ++k) wreg[k] = Wp[k*HD + lane];
    float bv = bp[lane], gv = gp[lane], bev = bep[lane];
    for (int row = r0; row < r1; ++row){
      float v = bv + dot32(xs + row*TF, wreg);
      s_acts[(obase + row)*HD + lane] = ln_relu(v, gv, bev);
    }
  }
  __syncthreads();

  // ---- 2 message-passing rounds ----
  for (int r = 0; r < 2; ++r){
    // zero the accumulator
    for (int i = t; i < NROWS*HD; i += BLK) s_acc[i] = 0.f;
    __syncthreads();

    const float* huWr = huW + r*128*HD;
    const float* vuWr = vuW + r*192*HD;
    const float* euWr = euW + r*128*HD;

    // task phase: 344 row-segments balanced 39-44 per wave
    switch (wv){
      case 0:
        run_task(huWr,          s_acts, s_acc, slot, nullptr, 0, 0,     0,     0,     0, 19, lane); // HU self
        run_task(huWr + 64*HD,  s_acts, s_acc, slot, h2v,     6, VBASE, 0,     0,     0, 19, lane); // HU gather
        run_task(euWr + 64*HD,  s_acts, s_acc, slot, e2v,     2, VBASE, 0,     EBASE, 66, 72, lane);
        break;
      case 1:
        run_task(vuWr,          s_acts, s_acc, slot, nullptr, 0, 0,     VBASE, VBASE, 0, 44, lane); // VU self
        break;
      case 2:
        run_task(vuWr + 64*HD,  s_acts, s_acc, slot, v2h,     3, 0,     0,     VBASE, 0, 44, lane); // VU from hex
        break;
      case 3:
        run_task(vuWr + 128*HD, s_acts, s_acc, slot, v2e,     3, EBASE, 0,     VBASE, 0, 44, lane); // VU from edge
        break;
      case 4:
        run_task(vuWr,          s_acts, s_acc, slot, nullptr, 0, 0,     VBASE, VBASE, 44, 54, lane);
        run_task(euWr,          s_acts, s_acc, slot, nullptr, 0, 0,     EBASE, EBASE, 0, 33, lane); // EU self
        break;
      case 5:
        run_task(vuWr + 64*HD,  s_acts, s_acc, slot, v2h,     3, 0,     0,     VBASE, 44, 54, lane);
        run_task(euWr,          s_acts, s_acc, slot, nullptr, 0, 0,     EBASE, EBASE, 33, 66, lane);
        break;
      case 6:
        run_task(vuWr + 128*HD, s_acts, s_acc, slot, v2e,     3, EBASE, 0,     VBASE, 44, 54, lane);
        run_task(euWr + 64*HD,  s_acts, s_acc, slot, e2v,     2, VBASE, 0,     EBASE, 0, 33, lane); // EU gather
        break;
      case 7:
        run_task(euWr,          s_acts, s_acc, slot, nullptr, 0, 0,     EBASE, EBASE, 66, 72, lane);
        run_task(euWr + 64*HD,  s_acts, s_acc, slot, e2v,     2, VBASE, 0,     EBASE, 33, 66, lane);
        break;
    }
    __syncthreads();

    // reduce phase: bias + LN + relu, in-place into acts
    {
      int rr0 = wv*19, rr1 = rr0 + 19 < NROWS ? rr0 + 19 : NROWS;
      for (int row = rr0; row < rr1; ++row){
        const float *bp, *gp, *bep;
        if (row < VBASE)      { bp = hub + r*HD; gp = hug + r*HD; bep = hube + r*HD; }
        else if (row < EBASE) { bp = vub + r*HD; gp = vug + r*HD; bep = vube + r*HD; }
        else                  { bp = eub + r*HD; gp = eug + r*HD; bep = eube + r*HD; }
        float v = s_acc[row*HD + lane] + bp[lane];
        s_acts[row*HD + lane] = ln_relu(v, gp[lane], bep[lane]);
      }
    }
    __syncthreads();
  }

  // ---- pooling (t<192) + zero readout acc (t 192..255) ----
  if (t < 192){
    int c = t & 63, ty = t >> 6;
    float s = 0.f;
    if (ty == 0){
      for (int n = 0; n < NHX; ++n) s += s_acts[n*HD + c];
      s *= (1.f/(float)NHX);
    } else if (ty == 1){
      for (int n = 0; n < NVX; ++n) s += s_acts[(VBASE+n)*HD + c];
      s *= (1.f/(float)NVX);
    } else {
      for (int n = 0; n < NED; ++n) s += s_acts[(EBASE+n)*HD + c];
      s *= (1.f/(float)NED);
    }
    s_pool[t] = s;
  } else if (t < 256){
    s_acc[t - 192] = 0.f;
  }
  __syncthreads();

  // ---- readout: 3 waves each do one 64-segment of K=192 ----
  if (wv < 3){
    float wreg[64];
#pragma unroll
    for (int k = 0; k < 64; ++k) wreg[k] = roW[(wv*64 + k)*HD + lane];
    float v = dot64(s_pool + wv*64, wreg);
    atomicAdd(&s_acc[lane], v);
  }
  __syncthreads();
  if (wv == 0){
    float v = s_acc[lane] + rob[lane];
    out[(size_t)b*HD + lane] = ln_relu(v, rog[lane], robe[lane]);
  }
}

extern "C" void kernel_launch(void* const* d_in, const int* in_sizes, int n_in,
                              void* d_out, int out_size, void* d_ws, size_t ws_size,
                              hipStream_t stream) {
  const float* tile = (const float*)d_in[0];
  const int* h2v  = (const int*)d_in[1];
  const int* v2h  = (const int*)d_in[2];
  const int* e2v  = (const int*)d_in[3];
  const int* v2e  = (const int*)d_in[4];
  const float* hinW = (const float*)d_in[5];
  const float* hinb = (const float*)d_in[6];
  const float* hing = (const float*)d_in[7];
  const float* hinbe= (const float*)d_in[8];
  const float* vinW = (const float*)d_in[9];
  const float* vinb = (const float*)d_in[10];
  const float* ving = (const float*)d_in[11];
  const float* vinbe= (const float*)d_in[12];
  const float* einW = (const float*)d_in[13];
  const float* einb = (const float*)d_in[14];
  const float* eing = (const float*)d_in[15];
  const float* einbe= (const float*)d_in[16];
  const float* huW  = (const float*)d_in[17];
  const float* hub  = (const float*)d_in[18];
  const float* hug  = (const float*)d_in[19];
  const float* hube = (const float*)d_in[20];
  const float* vuW  = (const float*)d_in[21];
  const float* vub  = (const float*)d_in[22];
  const float* vug  = (const float*)d_in[23];
  const float* vube = (const float*)d_in[24];
  const float* euW  = (const float*)d_in[25];
  const float* eub  = (const float*)d_in[26];
  const float* eug  = (const float*)d_in[27];
  const float* eube = (const float*)d_in[28];
  const float* roW  = (const float*)d_in[29];
  const float* rob  = (const float*)d_in[30];
  const float* rog  = (const float*)d_in[31];
  const float* robe = (const float*)d_in[32];
  float* out = (float*)d_out;

  int B = in_sizes[0] / (NHX*TF);   // 16384
  hipLaunchKernelGGL(graph_enc_kernel, dim3(B), dim3(BLK), 0, stream,
      tile, h2v, v2h, e2v, v2e,
      hinW, hinb, hing, hinbe,
      vinW, vinb, ving, vinbe,
      einW, einb, eing, einbe,
      huW, hub, hug, hube,
      vuW, vub, vug, vube,
      euW, eub, eug, eube,
      roW, rob, rog, robe,
      out);
}